// Round 3
// baseline (209.050 us; speedup 1.0000x reference)
//
#include <hip/hip_runtime.h>
#include <cmath>

namespace {

constexpr int Bn = 4;
constexpr int Cn = 3;
constexpr int Hn = 32, Wn = 32, Dn = 32;
constexpr int Kn = 16;
constexpr int Sn = 16;
constexpr int HOn = 30;
constexpr int Pn = HOn * HOn * HOn;       // 27000
constexpr int XCH = Hn * Wn * Dn;          // 32768 (one channel)
constexpr int XB  = Cn * XCH;              // 98304 (one batch)

typedef float v2f __attribute__((ext_vector_type(2)));

__device__ __constant__ float kMops[16][4] = {
    {0, 0, 0, 0},  {0, 0, 0, 1},  {0, 1, 0, -1}, {0, 1, 0, 0},
    {0, 0, 1, -1}, {0, 0, 1, 0},  {0, 1, 1, -2}, {0, 1, 1, -1},
    {1, -1, -1, 1},{1, -1, -1, 2},{1, 0, -1, 0}, {1, 0, -1, 1},
    {1, -1, 0, 0}, {1, -1, 0, 1}, {1, 0, 0, -1}, {1, 0, 0, 0}};

// r = c0 + c1*a + c2*b + c3*a*b, on a packed pair: 3 v_pk_fma_f32.
__device__ __forceinline__ v2f binop2(v2f a, v2f b, float4 c) {
    const v2f c0 = {c.x, c.x}, c1 = {c.y, c.y}, c2 = {c.z, c.z}, c3 = {c.w, c.w};
    const v2f t1 = __builtin_elementwise_fma(a, c3, c2);   // c3*a + c2
    const v2f t0 = __builtin_elementwise_fma(a, c1, c0);   // c1*a + c0
    return __builtin_elementwise_fma(b, t1, t0);
}

__global__ __launch_bounds__(256)
void logic_conv3d(const float* __restrict__ x,
                  const int* __restrict__ idx_a,
                  const int* __restrict__ idx_b,
                  const float* __restrict__ w0,
                  const float* __restrict__ w1,
                  const float* __restrict__ w2,
                  const float* __restrict__ w3,
                  const float* __restrict__ w4,
                  float* __restrict__ out) {
    const int k = blockIdx.y;
    const int tid = threadIdx.x;

    // 31 coefficient rows (float4 -> one ds_read_b128 each):
    // lvl0 n=0..15 -> rows 0..15, lvl1 -> 16..23, lvl2 -> 24..27,
    // lvl3 -> 28..29, lvl4 -> 30.
    __shared__ float4 coef4[31];
    __shared__ int2 baseab[Sn];  // .x = base_a[s], .y = base_b[s]

    // idx_a[k, p=0, s, :] == pa[k, s] because off[0] == (0,0,0,0) (PAD=0).
    if (tid < Sn) {
        const int* pa = idx_a + (((size_t)k * Pn) * Sn + tid) * 4;
        const int* pb = idx_b + (((size_t)k * Pn) * Sn + tid) * 4;
        int2 bb;
        bb.x = pa[3] * XCH + pa[0] * (Wn * Dn) + pa[1] * Dn + pa[2];
        bb.y = pb[3] * XCH + pb[0] * (Wn * Dn) + pb[1] * Dn + pb[2];
        baseab[tid] = bb;
    }
    if (tid < 31) {
        const float* wl;
        int n;
        if (tid < 16)      { wl = w0; n = tid; }
        else if (tid < 24) { wl = w1; n = tid - 16; }
        else if (tid < 28) { wl = w2; n = tid - 24; }
        else if (tid < 30) { wl = w3; n = tid - 28; }
        else               { wl = w4; n = 0; }
        const float* row = wl + (n * Kn + k) * 16;  // w_l[n, k, :]
        float e[16];
        float mx = row[0];
        #pragma unroll
        for (int o = 1; o < 16; ++o) mx = fmaxf(mx, row[o]);
        float sum = 0.f;
        #pragma unroll
        for (int o = 0; o < 16; ++o) { e[o] = expf(row[o] - mx); sum += e[o]; }
        const float inv = 1.0f / sum;
        float4 c;
        float acc;
        acc = 0.f;
        #pragma unroll
        for (int o = 0; o < 16; ++o) acc += e[o] * kMops[o][0];
        c.x = acc * inv;
        acc = 0.f;
        #pragma unroll
        for (int o = 0; o < 16; ++o) acc += e[o] * kMops[o][1];
        c.y = acc * inv;
        acc = 0.f;
        #pragma unroll
        for (int o = 0; o < 16; ++o) acc += e[o] * kMops[o][2];
        c.z = acc * inv;
        acc = 0.f;
        #pragma unroll
        for (int o = 0; o < 16; ++o) acc += e[o] * kMops[o][3];
        c.w = acc * inv;
        coef4[tid] = c;
    }
    __syncthreads();

    const int p = blockIdx.x * blockDim.x + tid;
    if (p >= Pn) return;

    // p = h0*900 + w0*30 + d0  (meshgrid 'ij', d fastest)
    const int h0 = p / 900;
    const int rem = p - h0 * 900;
    const int w0i = rem / 30;
    const int d0 = rem - w0i * 30;
    const int poff = h0 * (Wn * Dn) + w0i * Dn + d0;

    // Wave-uniform per-batch bases -> saddr-form loads with one 32-bit
    // voffset per (s, operand), reused across all 4 batches.
    const float* __restrict__ x0 = x;
    const float* __restrict__ x1 = x + XB;
    const float* __restrict__ x2 = x + 2 * XB;
    const float* __restrict__ x3 = x + 3 * XB;

    v2f v01[16];  // batches {0,1}
    v2f v23[16];  // batches {2,3}

    #pragma unroll
    for (int s = 0; s < 16; ++s) {
        const int2 bs = baseab[s];
        const int oa = bs.x + poff;
        const int ob = bs.y + poff;
        const float4 c = coef4[s];
        const v2f a01 = {x0[oa], x1[oa]};
        const v2f a23 = {x2[oa], x3[oa]};
        const v2f b01 = {x0[ob], x1[ob]};
        const v2f b23 = {x2[ob], x3[ob]};
        v01[s] = binop2(a01, b01, c);
        v23[s] = binop2(a23, b23, c);
    }
    #pragma unroll
    for (int n = 0; n < 8; ++n) {
        const float4 c = coef4[16 + n];
        v01[n] = binop2(v01[2 * n], v01[2 * n + 1], c);
        v23[n] = binop2(v23[2 * n], v23[2 * n + 1], c);
    }
    #pragma unroll
    for (int n = 0; n < 4; ++n) {
        const float4 c = coef4[24 + n];
        v01[n] = binop2(v01[2 * n], v01[2 * n + 1], c);
        v23[n] = binop2(v23[2 * n], v23[2 * n + 1], c);
    }
    #pragma unroll
    for (int n = 0; n < 2; ++n) {
        const float4 c = coef4[28 + n];
        v01[n] = binop2(v01[2 * n], v01[2 * n + 1], c);
        v23[n] = binop2(v23[2 * n], v23[2 * n + 1], c);
    }
    {
        const float4 c = coef4[30];
        const v2f r01 = binop2(v01[0], v01[1], c);
        const v2f r23 = binop2(v23[0], v23[1], c);
        const size_t kp = (size_t)k * Pn + p;
        out[kp]                      = r01.x;
        out[kp + (size_t)Kn * Pn]    = r01.y;
        out[kp + (size_t)2 * Kn * Pn] = r23.x;
        out[kp + (size_t)3 * Kn * Pn] = r23.y;
    }
}

}  // namespace

extern "C" void kernel_launch(void* const* d_in, const int* in_sizes, int n_in,
                              void* d_out, int out_size, void* d_ws, size_t ws_size,
                              hipStream_t stream) {
    const float* x     = (const float*)d_in[0];
    const int*   idx_a = (const int*)d_in[1];
    const int*   idx_b = (const int*)d_in[2];
    const float* w0    = (const float*)d_in[3];
    const float* w1    = (const float*)d_in[4];
    const float* w2    = (const float*)d_in[5];
    const float* w3    = (const float*)d_in[6];
    const float* w4    = (const float*)d_in[7];
    float* out = (float*)d_out;

    dim3 grid((Pn + 255) / 256, Kn);
    hipLaunchKernelGGL(logic_conv3d, grid, dim3(256), 0, stream,
                       x, idx_a, idx_b, w0, w1, w2, w3, w4, out);
}